// Round 11
// baseline (1385.628 us; speedup 1.0000x reference)
//
#include <hip/hip_runtime.h>
#include <stdint.h>

#define HH_ 64
#define WW_ 64
#define NB 4
#define CIN 1024
#define CMID 512
#define NANCH (HH_*WW_*9)      // 36864
#define PRE_N 6000
#define POST_N 300
#define CAND_PAD 6144
#define NEGV (-1.0e10f)
#define LO_SCL 2048.0f         // 2^11
#define LO_INV 4.8828125e-4f   // 2^-11
#define MWORDS 192             // CAND_PAD/32 suppression-mask words per row

typedef unsigned short u16;
typedef unsigned long long u64;
typedef __attribute__((ext_vector_type(8))) _Float16 f16x8;
typedef __attribute__((ext_vector_type(4))) float f32x4;

#define AS1 __attribute__((address_space(1)))
#define AS3 __attribute__((address_space(3)))

// ---------------- workspace layout (float units) ----------------
// total = 30,769,408 floats = 123.1 MB (validated working)
// NMS masks (18.9 MB) alias the X region: X is dead after heads_kernel.
#define X_OFF   0
#define X_SZ    (NB*CMID*HH_*WW_)        // 8,388,608
#define SC_OFF  (X_OFF + X_SZ)
#define SC_SZ   (NB*NANCH)               // 147,456
#define BX_OFF  (SC_OFF + SC_SZ)
#define BX_SZ   (NB*NANCH*4)             // 589,824
#define CSC_OFF (BX_OFF + BX_SZ)
#define CSC_SZ  (NB*CAND_PAD)
#define CBX_OFF (CSC_OFF + CSC_SZ)
#define CBX_SZ  (NB*CAND_PAD*4)
#define CIX_OFF (CBX_OFF + CBX_SZ)
#define CIX_SZ  (NB*CAND_PAD)
#define WTH_OFF (CIX_OFF + CIX_SZ)
#define WTH_SZ  (9*512*1024/2)           // fp16 hi weights [r][co][ci_perm]
#define WTL_OFF (WTH_OFF + WTH_SZ)
#define WTL_SZ  WTH_SZ
#define XH_OFF  (WTL_OFF + WTL_SZ)
#define XH_SZ   (NB*4096*1024/2)         // fp16 hi acts NHWC [b][sp][ci_perm]
#define XL_OFF  (XH_OFF + XH_SZ)
#define XL_SZ   XH_SZ
#define ZP_OFF  (XL_OFF + XL_SZ)
#define ZP_SZ   256

// ---------------- helpers ----------------
__device__ __forceinline__ void gl2lds16(const void* g, void* l) {
    __builtin_amdgcn_global_load_lds((const AS1 unsigned int*)g,
                                     (AS3 unsigned int*)l, 16, 0, 0);
}
union fh_u { _Float16 h; u16 u; };
__device__ __forceinline__ u16 f2h_hi(float x) {
    fh_u c; c.h = (_Float16)x; return c.u;
}
__device__ __forceinline__ u16 f2h_lo(float x, u16 hi) {
    fh_u c; c.u = hi;
    float hf = (float)c.h;
    fh_u d; d.h = (_Float16)((x - hf) * LO_SCL);
    return d.u;
}
// slot->channel map within each 32-chunk (matches MFMA per-lane k grouping).
__device__ __forceinline__ int cperm(int c) {
    int blk = c >> 5, w = c & 31;
    int pos = (w < 16) ? (((w >> 2) << 3) + (w & 3))
                       : ((((w - 16) >> 2) << 3) + 4 + (w & 3));
    return (blk << 5) + pos;
}
// order-preserving float->u32 (monotonic for all finite floats)
__device__ __forceinline__ unsigned fflip(unsigned u) {
    return (u & 0x80000000u) ? ~u : (u | 0x80000000u);
}

// =====================================================================
// Prep A: conv weights fp32 [co][ci][3][3] -> fp16 hi / scaled-lo
// [r][co][ci_perm]. No LDS -> full occupancy (R10's merged version
// capped weight blocks at LDS-limited occupancy).
// =====================================================================
__global__ __launch_bounds__(256) void prep_wtk(
    const float* __restrict__ conv_w, u16* __restrict__ WTH,
    u16* __restrict__ WTL, float* __restrict__ ZP)
{
    int o = blockIdx.x * 256 + threadIdx.x;      // < 4,718,592
    int ci = o & 1023, co = (o >> 10) & 511, r = o >> 19;
    float v = conv_w[((size_t)(co * 1024 + ci)) * 9 + r];
    u16 h  = f2h_hi(v);
    u16 lo = f2h_lo(v, h);
    size_t d = (((size_t)(r * 512 + co)) << 10) + cperm(ci);
    WTH[d] = h; WTL[d] = lo;
    if (o < 256) ZP[o] = 0.f;
}

// =====================================================================
// Prep B: activations fp32 NCHW -> fp16 hi/scaled-lo NHWC [b][sp][ci_perm]
// =====================================================================
__global__ __launch_bounds__(256) void prep_act(
    const float* __restrict__ in, u16* __restrict__ XH, u16* __restrict__ XL)
{
    __shared__ float T[64][65];
    const int blk = blockIdx.x;                  // 4 * 16 * 64 = 4096
    const int b   = blk >> 10;
    const int ci0 = ((blk >> 6) & 15) << 6;
    const int sp0 = (blk & 63) << 6;
    const int tid = threadIdx.x;
    const int tq  = tid >> 6;                    // 0..3
    const int t64 = tid & 63;
#pragma unroll
    for (int w = 0; w < 16; w++) {
        int ci_l = w * 4 + tq;
        T[ci_l][t64] = in[(((size_t)(b * 1024 + ci0 + ci_l)) << 12) + sp0 + t64];
    }
    __syncthreads();
#pragma unroll
    for (int w = 0; w < 16; w++) {
        int sp_l = w * 4 + tq;
        float x = T[t64][sp_l];
        u16 h  = f2h_hi(x);
        u16 lo = f2h_lo(x, h);
        size_t d = (((size_t)((b << 12) + sp0 + sp_l)) << 10) + ci0 + cperm(t64);
        XH[d] = h; XL[d] = lo;
    }
}

// =====================================================================
// Kernel 1: 3x3 conv as scaled-split-fp16 MFMA implicit GEMM.
// R9 swizzle (conflicts=0) + R10 issue order (ds_reads before prefetch)
// + R11 setprio(1) around MFMA cluster (T5; 2 blocks/CU gives wave
// role diversity). Output bit-identical to R8/R9/R10.
// =====================================================================
__global__ __launch_bounds__(256, 2) void conv3_mfma(
    const u16* __restrict__ WTH, const u16* __restrict__ WTL,
    const u16* __restrict__ XH, const u16* __restrict__ XL,
    const u16* __restrict__ ZP, const float* __restrict__ bias,
    float* __restrict__ Xout)
{
    __shared__ u16 Ah_s[2][4096];
    __shared__ u16 Al_s[2][4096];
    __shared__ u16 Bh_s[2][4096];
    __shared__ u16 Bl_s[2][4096];

    const int tid = threadIdx.x;
    const int bn  = blockIdx.x;              // 0..127
    const int bm  = blockIdx.y;              // 0..3
    const int l   = tid & 63;
    const int wid = tid >> 6, wm = wid >> 1, wn = wid & 1;

    const int rowq = tid >> 2;
    // pre-swizzled source chunk: physical p = tid&3 holds logical
    // chunk (tid&3) ^ ((rowq>>1)&3)
    const int c8   = (((tid & 3) ^ ((tid >> 3) & 3)) << 3);

    int spb[2]; unsigned vmq[2];
#pragma unroll
    for (int q = 0; q < 2; q++) {
        int n = bn * 128 + q * 64 + rowq;
        int yy = (n >> 6) & 63, xx = n & 63;
        spb[q] = n;
        unsigned m9 = 0;
#pragma unroll
        for (int rr = 0; rr < 9; rr++) {
            int dy = rr / 3 - 1, dx = rr % 3 - 1;
            if ((unsigned)(yy + dy) < 64u && (unsigned)(xx + dx) < 64u)
                m9 |= 1u << rr;
        }
        vmq[q] = m9;
    }

    f32x4 acc0[4][4], acc1[4][4];
#pragma unroll
    for (int i = 0; i < 4; i++)
#pragma unroll
        for (int j = 0; j < 4; j++) { acc0[i][j] = (f32x4)0.f; acc1[i][j] = (f32x4)0.f; }

    const int NK = 288;                      // 9216/32

    auto stage = [&](int sb, int kt) {
        const int r   = kt >> 5;
        const int ci0 = (kt & 31) << 5;
        const int kr  = (r * 11) >> 5;       // r/3 for r<9
        const int sh  = (kr - 1) * 64 + (r - 3 * kr - 1);
        const size_t wbase = (((size_t)(r * 512 + bm * 128)) << 10) + ci0 + c8;
        u16* ah = &Ah_s[sb][tid * 8];
        u16* al = &Al_s[sb][tid * 8];
        u16* bh = &Bh_s[sb][tid * 8];
        u16* bl = &Bl_s[sb][tid * 8];
#pragma unroll
        for (int q = 0; q < 2; q++) {
            const size_t aoff = wbase + (((size_t)(q * 64 + rowq)) << 10);
            gl2lds16(WTH + aoff, ah + q * 2048);
            gl2lds16(WTL + aoff, al + q * 2048);
            const bool v = (vmq[q] >> r) & 1u;
            const size_t boff = (((size_t)(spb[q] + sh)) << 10) + ci0 + c8;
            gl2lds16(v ? (XH + boff) : ZP, bh + q * 2048);
            gl2lds16(v ? (XL + boff) : ZP, bl + q * 2048);
        }
    };

    // fragment read addresses (loop-invariant)
    const int lo16 = l & 15, hi4 = l >> 4;
    const int swl  = (lo16 >> 1) & 3;
    const int pch  = (hi4 ^ swl) << 3;
    const int aoff = (wm * 64 + lo16) * 32 + pch;
    const int boff = (wn * 64 + lo16) * 32 + pch;

    stage(0, 0);
    int buf = 0;
    for (int kt = 0; kt < NK; ++kt) {
        __syncthreads();
        // DS reads first (current tile fragments)
        f16x8 ah[4], av[4], bh[4], bv[4];
#pragma unroll
        for (int i = 0; i < 4; i++) {
            ah[i] = *(const f16x8*)&Ah_s[buf][aoff + i * 512];
            av[i] = *(const f16x8*)&Al_s[buf][aoff + i * 512];
            bh[i] = *(const f16x8*)&Bh_s[buf][boff + i * 512];
            bv[i] = *(const f16x8*)&Bl_s[buf][boff + i * 512];
        }
        // then issue next-tile prefetch (VMEM overlaps MFMA + lgkm waits)
        if (kt + 1 < NK) stage(buf ^ 1, kt + 1);
        __builtin_amdgcn_s_setprio(1);
#pragma unroll
        for (int mi = 0; mi < 4; mi++)
#pragma unroll
            for (int ni = 0; ni < 4; ni++) {
                acc0[mi][ni] = __builtin_amdgcn_mfma_f32_16x16x32_f16(
                    ah[mi], bh[ni], acc0[mi][ni], 0, 0, 0);
                acc1[mi][ni] = __builtin_amdgcn_mfma_f32_16x16x32_f16(
                    ah[mi], bv[ni], acc1[mi][ni], 0, 0, 0);
                acc1[mi][ni] = __builtin_amdgcn_mfma_f32_16x16x32_f16(
                    av[mi], bh[ni], acc1[mi][ni], 0, 0, 0);
            }
        __builtin_amdgcn_s_setprio(0);
        buf ^= 1;
    }

    // epilogue: combine + bias + relu -> X NCHW fp32.
#pragma unroll
    for (int mi = 0; mi < 4; mi++) {
        const int co0 = bm * 128 + wm * 64 + mi * 16 + ((l >> 4) << 2);
        const f32x4 b4 = *(const f32x4*)&bias[co0];
#pragma unroll
        for (int ni = 0; ni < 4; ni++) {
            const int n = bn * 128 + wn * 64 + ni * 16 + (l & 15);
            const int b = n >> 12, sp = n & 4095;
            f32x4 v0 = acc0[mi][ni], v1 = acc1[mi][ni];
            float* xo = Xout + (((size_t)(b * 512 + co0)) << 12) + sp;
            xo[0]        = fmaxf(fmaf(v1[0], LO_INV, v0[0]) + b4[0], 0.f);
            xo[4096]     = fmaxf(fmaf(v1[1], LO_INV, v0[1]) + b4[1], 0.f);
            xo[2 * 4096] = fmaxf(fmaf(v1[2], LO_INV, v0[2]) + b4[2], 0.f);
            xo[3 * 4096] = fmaxf(fmaf(v1[3], LO_INV, v0[3]) + b4[3], 0.f);
        }
    }
}

// =====================================================================
// Kernel 2: 1x1 heads v4 -- 64 blocks x 256 thr, NO LDS: W addresses
// are wave-uniform (no tid dependence) so reads go through the scalar
// cache (s_load), freeing the vector pipe; zero barriers. Per-thread
// FMA order unchanged (ci ascending, same nest) -> bit-identical.
// =====================================================================
__global__ __launch_bounds__(256) void heads_kernel(
    const float* __restrict__ X, const float* __restrict__ cls_w,
    const float* __restrict__ cls_b, const float* __restrict__ bbox_w,
    const float* __restrict__ bbox_b, const float* __restrict__ im_info,
    float* __restrict__ SC, float* __restrict__ BXo)
{
    const int tid = threadIdx.x;
    const int blk = blockIdx.x;            // 0..63
    const int b   = blk >> 4;
    const int s   = ((blk & 15) << 8) + tid;

    float acc[54];
#pragma unroll
    for (int j = 0; j < 18; j++) acc[j] = cls_b[j];
#pragma unroll
    for (int j = 0; j < 36; j++) acc[18 + j] = bbox_b[j];

    const float* xp = X + (size_t)b * CMID * 4096 + s;
    for (int ci = 0; ci < 512; ci += 4) {
        float x0 = xp[(size_t)(ci) * 4096];
        float x1 = xp[(size_t)(ci + 1) * 4096];
        float x2 = xp[(size_t)(ci + 2) * 4096];
        float x3 = xp[(size_t)(ci + 3) * 4096];
#pragma unroll
        for (int j = 0; j < 54; j++) {
            const float* wp = (j < 18) ? (cls_w + j * 512 + ci)
                                       : (bbox_w + (j - 18) * 512 + ci);
            float4 w4 = *(const float4*)wp;       // uniform -> s_load
            acc[j] = fmaf(x3, w4.w, fmaf(x2, w4.z, fmaf(x1, w4.y, fmaf(x0, w4.x, acc[j]))));
        }
    }

    const float imh = im_info[b * 3 + 0];
    const float imw = im_info[b * 3 + 1];
    const int hh = s >> 6, ww = s & 63;
    const float cxa = 7.5f + 16.f * (float)ww;
    const float cya = 7.5f + 16.f * (float)hh;
    const float WA[9] = {184.f, 368.f, 736.f, 128.f, 256.f, 512.f, 88.f, 176.f, 352.f};
    const float HA[9] = {96.f, 192.f, 384.f, 128.f, 256.f, 512.f, 176.f, 352.f, 704.f};
    const size_t base = (size_t)b * NANCH + (size_t)s * 9;
#pragma unroll
    for (int c = 0; c < 9; c++) {
        float bg = acc[c], fg = acc[9 + c];
        float m  = fmaxf(bg, fg);
        float e0 = expf(bg - m), e1 = expf(fg - m);
        float p  = e1 / (e0 + e1);
        float dx = acc[18 + 4 * c], dy = acc[19 + 4 * c];
        float dw = acc[20 + 4 * c], dh = acc[21 + 4 * c];
        float wa = WA[c], ha = HA[c];
        float cx = dx * wa + cxa;
        float cy = dy * ha + cya;
        float pw = expf(dw) * wa;
        float ph = expf(dh) * ha;
        float x1 = cx - 0.5f * pw, y1 = cy - 0.5f * ph;
        float x2 = cx + 0.5f * pw, y2 = cy + 0.5f * ph;
        x1 = fminf(fmaxf(x1, 0.f), imw - 1.f);
        y1 = fminf(fmaxf(y1, 0.f), imh - 1.f);
        x2 = fminf(fmaxf(x2, 0.f), imw - 1.f);
        y2 = fminf(fmaxf(y2, 0.f), imh - 1.f);
        SC[base + c] = p;
        *(float4*)&BXo[(base + c) * 4] = make_float4(x1, y1, x2, y2);
    }
}

// =====================================================================
// Kernel 3: selsort (proven R10) -- radix-find ustar, compact >= ustar,
// bitonic sort desc (skewed), truncate at 6000 = exact ref top-6000.
// =====================================================================
__global__ __launch_bounds__(1024) void selsort_kernel(
    const float* __restrict__ SC, const float* __restrict__ BX,
    float* __restrict__ CSC, float* __restrict__ CBX, int* __restrict__ CIX)
{
    const int b = blockIdx.x, tid = threadIdx.x;
    const int lane = tid & 63, wv = tid >> 6;
    const float* sc = SC + (size_t)b * NANCH;
    const unsigned* bits = (const unsigned*)sc;

    __shared__ u64 sk[8704];                 // keys (skewed); u32 view = hist
    unsigned* s_buf = (unsigned*)sk;         // 8192 u32 = 32KB subset
    __shared__ unsigned s_part[1024];
    __shared__ unsigned s_wsum[16];
    __shared__ unsigned s_sel[2];
    __shared__ int s_cnt;
    auto P = [](int i) { return i + (i >> 4); };

    auto findbin = [&](int nb, int bpt, unsigned target) -> uint2 {
        unsigned mysum = 0;
        const int base = tid * bpt;
        if (base < nb)
            for (int q = 0; q < bpt; q++) mysum += s_buf[base + q];
        s_part[tid] = mysum;
        unsigned wsum = mysum;
#pragma unroll
        for (int off = 32; off; off >>= 1) wsum += __shfl_down(wsum, off);
        if (lane == 0) s_wsum[wv] = wsum;
        __syncthreads();
        unsigned cum = 0;
        for (int w = wv + 1; w < 16; w++) cum += s_wsum[w];
        for (int ll = lane + 1; ll < 64; ll++) cum += s_part[(wv << 6) + ll];
        if (base < nb) {
            unsigned c = cum;
            for (int q = bpt - 1; q >= 0; q--) {
                unsigned h = s_buf[base + q];
                if (c < target && c + h >= target) { s_sel[0] = base + q; s_sel[1] = c; }
                c += h;
            }
        }
        __syncthreads();
        uint2 r; r.x = s_sel[0]; r.y = s_sel[1];
        __syncthreads();
        return r;
    };

    // ---- 3-level radix to find ustar (6000th-largest raw bits) ----
    for (int i = tid; i < 8192; i += 1024) s_buf[i] = 0;
    __syncthreads();
    for (int i = tid; i < NANCH; i += 1024)
        atomicAdd(&s_buf[bits[i] >> 19], 1u);
    __syncthreads();
    uint2 r1 = findbin(8192, 8, PRE_N);
    const unsigned B1 = r1.x;
    unsigned target2 = PRE_N - r1.y;

    for (int i = tid; i < 8192; i += 1024) s_buf[i] = 0;
    __syncthreads();
    for (int i = tid; i < NANCH; i += 1024) {
        unsigned u = bits[i];
        if ((u >> 19) == B1) atomicAdd(&s_buf[(u >> 6) & 8191u], 1u);
    }
    __syncthreads();
    uint2 r2 = findbin(8192, 8, target2);
    const unsigned B2 = r2.x;
    unsigned target3 = target2 - r2.y;

    if (tid < 64) s_buf[tid] = 0;
    __syncthreads();
    const unsigned pref26 = (B1 << 13) | B2;
    for (int i = tid; i < NANCH; i += 1024) {
        unsigned u = bits[i];
        if ((u >> 6) == pref26) atomicAdd(&s_buf[u & 63u], 1u);
    }
    __syncthreads();
    uint2 r3 = findbin(64, 1, target3);
    const unsigned ustar = (B1 << 19) | (B2 << 6) | r3.x;

    // ---- compact all >= ustar into keys (count >= 6000 guaranteed) ----
    for (int i = tid; i < 8704; i += 1024) sk[i] = 0ull;   // filler sorts last
    if (tid == 0) s_cnt = 0;
    __syncthreads();
    for (int i = tid; i < NANCH; i += 1024) {
        unsigned u = bits[i];
        if (u >= ustar) {
            int p = atomicAdd(&s_cnt, 1);
            if (p < 8192)
                sk[P(p)] = ((u64)fflip(u) << 32) | (u64)(~((unsigned)i));
        }
    }
    __syncthreads();

    // ---- bitonic sort descending over 8192 (skewed index) ----
    for (int k = 2; k <= 8192; k <<= 1) {
        for (int j = k >> 1; j > 0; j >>= 1) {
            for (int t = tid; t < 8192; t += 1024) {
                int ixj = t ^ j;
                if (ixj > t) {
                    int pa = P(t), pb = P(ixj);
                    u64 a = sk[pa], c2 = sk[pb];
                    bool up = ((t & k) == 0);
                    if ((a < c2) == up) { sk[pa] = c2; sk[pb] = a; }
                }
            }
            __syncthreads();
        }
    }

    // ---- output: ranks < 6000 real (gather box), rest padded ----
    float* csc = CSC + (size_t)b * CAND_PAD;
    int*   cix = CIX + (size_t)b * CAND_PAD;
    float4* cbx4 = (float4*)CBX + (size_t)b * CAND_PAD;
    const float4* bx4 = (const float4*)BX + (size_t)b * NANCH;
    for (int i = tid; i < CAND_PAD; i += 1024) {
        if (i < PRE_N) {
            u64 key = sk[P(i)];
            unsigned khi = (unsigned)(key >> 32), klo = (unsigned)key;
            unsigned su = (khi & 0x80000000u) ? (khi ^ 0x80000000u) : ~khi;
            float scv = __uint_as_float(su);
            int ci = (int)(~klo);
            csc[i] = scv; cix[i] = ci;
            float4 pb;
            if (scv > -5.0e9f && (unsigned)ci < (unsigned)NANCH) pb = bx4[ci];
            else pb = make_float4(-4e9f, -4e9f, -4e9f, -4e9f);
            cbx4[i] = pb;
        } else {
            csc[i] = -2.0e10f;
            cix[i] = 0x7fffffff;
            cbx4[i] = make_float4(-4e9f, -4e9f, -4e9f, -4e9f);
        }
    }
}

// =====================================================================
// Kernel 4b: pairwise suppression bitmasks (proven).
// =====================================================================
__global__ __launch_bounds__(256) void nms_mask(
    const float* __restrict__ CBX, unsigned* __restrict__ MASK)
{
    const int rg = blockIdx.x, b = blockIdx.y, tid = threadIdx.x;
    const float4* cbx = (const float4*)CBX + (size_t)b * CAND_PAD;
    unsigned* mrow = MASK + (size_t)b * CAND_PAD * MWORDS;

    __shared__ float4 rb[64];
    __shared__ float  rar[64];
    __shared__ float4 cb[1024];
    __shared__ float  car[1024];

    if (tid < 64) {
        float4 v = cbx[rg * 64 + tid];
        rb[tid] = v;
        rar[tid] = (v.z - v.x + 1.f) * (v.w - v.y + 1.f);
    }
    __syncthreads();
    const int rl = tid >> 2;                  // row 0..63 within group
    const int wq = tid & 3;
    const float4 rv = rb[rl];
    const float  ra = rar[rl];
    const size_t rbase = (size_t)(rg * 64 + rl) * MWORDS;

    for (int jt = rg >> 4; jt < 6; jt++) {    // skip strictly-lower tiles
        __syncthreads();
        for (int e = tid; e < 1024; e += 256) {
            float4 v = cbx[jt * 1024 + e];
            cb[e] = v;
            car[e] = (v.z - v.x + 1.f) * (v.w - v.y + 1.f);
        }
        __syncthreads();
#pragma unroll
        for (int k = 0; k < 8; k++) {
            const int wt = wq + 4 * k;        // word in tile 0..31
            unsigned bits = 0;
            for (int bit = 0; bit < 32; bit++) {
                const int j = wt * 32 + bit;
                float4 cv = cb[j];
                float xx1 = fmaxf(rv.x, cv.x);
                float yy1 = fmaxf(rv.y, cv.y);
                float xx2 = fminf(rv.z, cv.z);
                float yy2 = fminf(rv.w, cv.w);
                float iw = fmaxf(xx2 - xx1 + 1.f, 0.f);
                float ih = fmaxf(yy2 - yy1 + 1.f, 0.f);
                float inter = iw * ih;
                float iou = inter / (ra + car[j] - inter);
                if (iou > 0.7f) bits |= (1u << bit);
            }
            mrow[rbase + jt * 32 + wt] = bits;
        }
    }
}

// =====================================================================
// Kernel 4c: scan v3 (proven) -- single wave, register removed-mask.
// =====================================================================
__global__ __launch_bounds__(64) void nms_scan(
    const float* __restrict__ CSC, const float* __restrict__ CBX,
    const unsigned* __restrict__ MASK, float* __restrict__ out)
{
    const int b = blockIdx.x, lane = threadIdx.x;
    const float*  csc = CSC + (size_t)b * CAND_PAD;
    const float4* cbx = (const float4*)CBX + (size_t)b * CAND_PAD;
    const unsigned* mk = MASK + (size_t)b * CAND_PAD * MWORDS;

    float* rois = out + (size_t)b * 1500;
    float* oscr = out + 6000 + (size_t)b * 300;

    for (int it = lane; it < POST_N; it += 64) {
        float* r = rois + it * 5;
        r[0] = (float)b; r[1] = 0.f; r[2] = 0.f; r[3] = 0.f; r[4] = 0.f;
        oscr[it] = 0.f;
    }
    __syncthreads();

    unsigned rm0 = 0u, rm1 = 0u, rm2 = 0u;   // removed words lane,+64,+128
    int cnt = 0;
    unsigned rlo = mk[(size_t)lane * MWORDS + 0];
    unsigned rhi = mk[(size_t)lane * MWORDS + 1];
    float    rsc = csc[lane];

    for (int c = 0; c < 94 && cnt < POST_N; c++) {
        const int W0 = 2 * c;
        const int slot = W0 >> 6;
        unsigned sel = (slot == 0) ? rm0 : (slot == 1) ? rm1 : rm2;
        unsigned gw = __shfl(sel, (W0 & 63) + (lane >> 5));
        bool alive = !((gw >> (lane & 31)) & 1u) && (rsc > -5.0e9f);
        u64 rem = __ballot(alive);
        u64 keptm = 0ull;
        while (rem) {
            int sl = __builtin_ctzll(rem);
            keptm |= 1ull << sl;
            unsigned blo = __shfl(rlo, sl);
            unsigned bhi = __shfl(rhi, sl);
            rem &= ~(((u64)bhi << 32) | (u64)blo);
            rem &= ~(1ull << sl);
        }
        if (c + 1 < 94) {
            const int i2 = (c + 1) * 64 + lane;
            rlo = mk[(size_t)i2 * MWORDS + 2 * (c + 1)];
            rhi = mk[(size_t)i2 * MWORDS + 2 * (c + 1) + 1];
            rsc = csc[i2];
        }
        while (keptm && cnt < POST_N) {
            int sl = __builtin_ctzll(keptm);
            keptm &= keptm - 1ull;
            const int i = c * 64 + sl;
            const size_t rb = (size_t)i * MWORDS;
            rm0 |= mk[rb + lane];
            rm1 |= mk[rb + lane + 64];
            rm2 |= mk[rb + lane + 128];
            if (lane == 0) {
                float4 pb = cbx[i];
                float* r = rois + cnt * 5;
                r[1] = pb.x; r[2] = pb.y; r[3] = pb.z; r[4] = pb.w;
                oscr[cnt] = csc[i];
            }
            cnt++;
        }
    }
}

// =====================================================================
extern "C" void kernel_launch(void* const* d_in, const int* in_sizes, int n_in,
                              void* d_out, int out_size, void* d_ws, size_t ws_size,
                              hipStream_t stream)
{
    const float* base_feat = (const float*)d_in[0];
    const float* im_info   = (const float*)d_in[1];
    const float* conv_w    = (const float*)d_in[4];
    const float* conv_b    = (const float*)d_in[5];
    const float* cls_w     = (const float*)d_in[6];
    const float* cls_b     = (const float*)d_in[7];
    const float* bbox_w    = (const float*)d_in[8];
    const float* bbox_b    = (const float*)d_in[9];

    float* ws  = (float*)d_ws;
    float* X   = ws + X_OFF;
    float* SC  = ws + SC_OFF;
    float* BX  = ws + BX_OFF;
    float* CSC = ws + CSC_OFF;
    float* CBX = ws + CBX_OFF;
    int*   CIX = (int*)(ws + CIX_OFF);
    u16*   WTH = (u16*)(ws + WTH_OFF);
    u16*   WTL = (u16*)(ws + WTL_OFF);
    u16*   XHp = (u16*)(ws + XH_OFF);
    u16*   XLp = (u16*)(ws + XL_OFF);
    float* ZPf = ws + ZP_OFF;
    const u16* ZPu = (const u16*)ZPf;
    unsigned* MASK = (unsigned*)(ws + X_OFF);   // aliases X (dead after heads)
    float* out = (float*)d_out;

    hipLaunchKernelGGL(prep_wtk, dim3(18432), dim3(256), 0, stream,
                       conv_w, WTH, WTL, ZPf);
    hipLaunchKernelGGL(prep_act, dim3(4096), dim3(256), 0, stream,
                       base_feat, XHp, XLp);
    hipLaunchKernelGGL(conv3_mfma, dim3(128, 4), dim3(256), 0, stream,
                       WTH, WTL, XHp, XLp, ZPu, conv_b, X);
    hipLaunchKernelGGL(heads_kernel, dim3(64), dim3(256), 0, stream,
                       X, cls_w, cls_b, bbox_w, bbox_b, im_info, SC, BX);
    hipLaunchKernelGGL(selsort_kernel, dim3(4), dim3(1024), 0, stream,
                       SC, BX, CSC, CBX, CIX);
    hipLaunchKernelGGL(nms_mask, dim3(96, 4), dim3(256), 0, stream,
                       CBX, MASK);
    hipLaunchKernelGGL(nms_scan, dim3(4), dim3(64), 0, stream,
                       CSC, CBX, MASK, out);
}

// Round 12
// 1164.436 us; speedup vs baseline: 1.1900x; 1.1900x over previous
//
#include <hip/hip_runtime.h>
#include <stdint.h>

#define HH_ 64
#define WW_ 64
#define NB 4
#define CIN 1024
#define CMID 512
#define NANCH (HH_*WW_*9)      // 36864
#define PRE_N 6000
#define POST_N 300
#define CAND_PAD 6144
#define NEGV (-1.0e10f)
#define LO_SCL 2048.0f         // 2^11
#define LO_INV 4.8828125e-4f   // 2^-11
#define MWORDS 192             // CAND_PAD/32 suppression-mask words per row

typedef unsigned short u16;
typedef unsigned long long u64;
typedef __attribute__((ext_vector_type(8))) _Float16 f16x8;
typedef __attribute__((ext_vector_type(4))) float f32x4;

#define AS1 __attribute__((address_space(1)))
#define AS3 __attribute__((address_space(3)))

// ---------------- workspace layout (float units) ----------------
// total = 30,769,408 floats = 123.1 MB (validated working)
// NMS masks (18.9 MB) alias the X region: X is dead after heads_kernel.
#define X_OFF   0
#define X_SZ    (NB*CMID*HH_*WW_)        // 8,388,608
#define SC_OFF  (X_OFF + X_SZ)
#define SC_SZ   (NB*NANCH)               // 147,456
#define BX_OFF  (SC_OFF + SC_SZ)
#define BX_SZ   (NB*NANCH*4)             // 589,824
#define CSC_OFF (BX_OFF + BX_SZ)
#define CSC_SZ  (NB*CAND_PAD)
#define CBX_OFF (CSC_OFF + CSC_SZ)
#define CBX_SZ  (NB*CAND_PAD*4)
#define CIX_OFF (CBX_OFF + CBX_SZ)
#define CIX_SZ  (NB*CAND_PAD)
#define WTH_OFF (CIX_OFF + CIX_SZ)
#define WTH_SZ  (9*512*1024/2)           // fp16 hi weights [r][co][ci_perm]
#define WTL_OFF (WTH_OFF + WTH_SZ)
#define WTL_SZ  WTH_SZ
#define XH_OFF  (WTL_OFF + WTL_SZ)
#define XH_SZ   (NB*4096*1024/2)         // fp16 hi acts NHWC [b][sp][ci_perm]
#define XL_OFF  (XH_OFF + XH_SZ)
#define XL_SZ   XH_SZ
#define ZP_OFF  (XL_OFF + XL_SZ)
#define ZP_SZ   256

// ---------------- helpers ----------------
__device__ __forceinline__ void gl2lds16(const void* g, void* l) {
    __builtin_amdgcn_global_load_lds((const AS1 unsigned int*)g,
                                     (AS3 unsigned int*)l, 16, 0, 0);
}
union fh_u { _Float16 h; u16 u; };
__device__ __forceinline__ u16 f2h_hi(float x) {
    fh_u c; c.h = (_Float16)x; return c.u;
}
__device__ __forceinline__ u16 f2h_lo(float x, u16 hi) {
    fh_u c; c.u = hi;
    float hf = (float)c.h;
    fh_u d; d.h = (_Float16)((x - hf) * LO_SCL);
    return d.u;
}
// slot->channel map within each 32-chunk (matches MFMA per-lane k grouping).
__device__ __forceinline__ int cperm(int c) {
    int blk = c >> 5, w = c & 31;
    int pos = (w < 16) ? (((w >> 2) << 3) + (w & 3))
                       : ((((w - 16) >> 2) << 3) + 4 + (w & 3));
    return (blk << 5) + pos;
}
// order-preserving float->u32 (monotonic for all finite floats)
__device__ __forceinline__ unsigned fflip(unsigned u) {
    return (u & 0x80000000u) ? ~u : (u | 0x80000000u);
}

// =====================================================================
// Prep A: conv weights fp32 [co][ci][3][3] -> fp16 hi / scaled-lo
// [r][co][ci_perm]. No LDS.
// =====================================================================
__global__ __launch_bounds__(256) void prep_wtk(
    const float* __restrict__ conv_w, u16* __restrict__ WTH,
    u16* __restrict__ WTL, float* __restrict__ ZP)
{
    int o = blockIdx.x * 256 + threadIdx.x;      // < 4,718,592
    int ci = o & 1023, co = (o >> 10) & 511, r = o >> 19;
    float v = conv_w[((size_t)(co * 1024 + ci)) * 9 + r];
    u16 h  = f2h_hi(v);
    u16 lo = f2h_lo(v, h);
    size_t d = (((size_t)(r * 512 + co)) << 10) + cperm(ci);
    WTH[d] = h; WTL[d] = lo;
    if (o < 256) ZP[o] = 0.f;
}

// =====================================================================
// Prep B: activations fp32 NCHW -> fp16 hi/scaled-lo NHWC [b][sp][ci_perm]
// =====================================================================
__global__ __launch_bounds__(256) void prep_act(
    const float* __restrict__ in, u16* __restrict__ XH, u16* __restrict__ XL)
{
    __shared__ float T[64][65];
    const int blk = blockIdx.x;                  // 4 * 16 * 64 = 4096
    const int b   = blk >> 10;
    const int ci0 = ((blk >> 6) & 15) << 6;
    const int sp0 = (blk & 63) << 6;
    const int tid = threadIdx.x;
    const int tq  = tid >> 6;                    // 0..3
    const int t64 = tid & 63;
#pragma unroll
    for (int w = 0; w < 16; w++) {
        int ci_l = w * 4 + tq;
        T[ci_l][t64] = in[(((size_t)(b * 1024 + ci0 + ci_l)) << 12) + sp0 + t64];
    }
    __syncthreads();
#pragma unroll
    for (int w = 0; w < 16; w++) {
        int sp_l = w * 4 + tq;
        float x = T[t64][sp_l];
        u16 h  = f2h_hi(x);
        u16 lo = f2h_lo(x, h);
        size_t d = (((size_t)((b << 12) + sp0 + sp_l)) << 10) + ci0 + cperm(t64);
        XH[d] = h; XL[d] = lo;
    }
}

// =====================================================================
// Kernel 1: 3x3 conv as scaled-split-fp16 MFMA implicit GEMM.
// R9 swizzle (conflicts=0) + R10 issue order (ds_reads before
// prefetch). setprio removed (R11: neutral, cost VGPRs). Output
// bit-identical to R8-R11.
// =====================================================================
__global__ __launch_bounds__(256, 2) void conv3_mfma(
    const u16* __restrict__ WTH, const u16* __restrict__ WTL,
    const u16* __restrict__ XH, const u16* __restrict__ XL,
    const u16* __restrict__ ZP, const float* __restrict__ bias,
    float* __restrict__ Xout)
{
    __shared__ u16 Ah_s[2][4096];
    __shared__ u16 Al_s[2][4096];
    __shared__ u16 Bh_s[2][4096];
    __shared__ u16 Bl_s[2][4096];

    const int tid = threadIdx.x;
    const int bn  = blockIdx.x;              // 0..127
    const int bm  = blockIdx.y;              // 0..3
    const int l   = tid & 63;
    const int wid = tid >> 6, wm = wid >> 1, wn = wid & 1;

    const int rowq = tid >> 2;
    // pre-swizzled source chunk: physical p = tid&3 holds logical
    // chunk (tid&3) ^ ((rowq>>1)&3)
    const int c8   = (((tid & 3) ^ ((tid >> 3) & 3)) << 3);

    int spb[2]; unsigned vmq[2];
#pragma unroll
    for (int q = 0; q < 2; q++) {
        int n = bn * 128 + q * 64 + rowq;
        int yy = (n >> 6) & 63, xx = n & 63;
        spb[q] = n;
        unsigned m9 = 0;
#pragma unroll
        for (int rr = 0; rr < 9; rr++) {
            int dy = rr / 3 - 1, dx = rr % 3 - 1;
            if ((unsigned)(yy + dy) < 64u && (unsigned)(xx + dx) < 64u)
                m9 |= 1u << rr;
        }
        vmq[q] = m9;
    }

    f32x4 acc0[4][4], acc1[4][4];
#pragma unroll
    for (int i = 0; i < 4; i++)
#pragma unroll
        for (int j = 0; j < 4; j++) { acc0[i][j] = (f32x4)0.f; acc1[i][j] = (f32x4)0.f; }

    const int NK = 288;                      // 9216/32

    auto stage = [&](int sb, int kt) {
        const int r   = kt >> 5;
        const int ci0 = (kt & 31) << 5;
        const int kr  = (r * 11) >> 5;       // r/3 for r<9
        const int sh  = (kr - 1) * 64 + (r - 3 * kr - 1);
        const size_t wbase = (((size_t)(r * 512 + bm * 128)) << 10) + ci0 + c8;
        u16* ah = &Ah_s[sb][tid * 8];
        u16* al = &Al_s[sb][tid * 8];
        u16* bh = &Bh_s[sb][tid * 8];
        u16* bl = &Bl_s[sb][tid * 8];
#pragma unroll
        for (int q = 0; q < 2; q++) {
            const size_t aoff = wbase + (((size_t)(q * 64 + rowq)) << 10);
            gl2lds16(WTH + aoff, ah + q * 2048);
            gl2lds16(WTL + aoff, al + q * 2048);
            const bool v = (vmq[q] >> r) & 1u;
            const size_t boff = (((size_t)(spb[q] + sh)) << 10) + ci0 + c8;
            gl2lds16(v ? (XH + boff) : ZP, bh + q * 2048);
            gl2lds16(v ? (XL + boff) : ZP, bl + q * 2048);
        }
    };

    // fragment read addresses (loop-invariant)
    const int lo16 = l & 15, hi4 = l >> 4;
    const int swl  = (lo16 >> 1) & 3;
    const int pch  = (hi4 ^ swl) << 3;
    const int aoff = (wm * 64 + lo16) * 32 + pch;
    const int boff = (wn * 64 + lo16) * 32 + pch;

    stage(0, 0);
    int buf = 0;
    for (int kt = 0; kt < NK; ++kt) {
        __syncthreads();
        // DS reads first (current tile fragments)
        f16x8 ah[4], av[4], bh[4], bv[4];
#pragma unroll
        for (int i = 0; i < 4; i++) {
            ah[i] = *(const f16x8*)&Ah_s[buf][aoff + i * 512];
            av[i] = *(const f16x8*)&Al_s[buf][aoff + i * 512];
            bh[i] = *(const f16x8*)&Bh_s[buf][boff + i * 512];
            bv[i] = *(const f16x8*)&Bl_s[buf][boff + i * 512];
        }
        // then issue next-tile prefetch (VMEM overlaps MFMA + lgkm waits)
        if (kt + 1 < NK) stage(buf ^ 1, kt + 1);
#pragma unroll
        for (int mi = 0; mi < 4; mi++)
#pragma unroll
            for (int ni = 0; ni < 4; ni++) {
                acc0[mi][ni] = __builtin_amdgcn_mfma_f32_16x16x32_f16(
                    ah[mi], bh[ni], acc0[mi][ni], 0, 0, 0);
                acc1[mi][ni] = __builtin_amdgcn_mfma_f32_16x16x32_f16(
                    ah[mi], bv[ni], acc1[mi][ni], 0, 0, 0);
                acc1[mi][ni] = __builtin_amdgcn_mfma_f32_16x16x32_f16(
                    av[mi], bh[ni], acc1[mi][ni], 0, 0, 0);
            }
        buf ^= 1;
    }

    // epilogue: combine + bias + relu -> X NCHW fp32.
#pragma unroll
    for (int mi = 0; mi < 4; mi++) {
        const int co0 = bm * 128 + wm * 64 + mi * 16 + ((l >> 4) << 2);
        const f32x4 b4 = *(const f32x4*)&bias[co0];
#pragma unroll
        for (int ni = 0; ni < 4; ni++) {
            const int n = bn * 128 + wn * 64 + ni * 16 + (l & 15);
            const int b = n >> 12, sp = n & 4095;
            f32x4 v0 = acc0[mi][ni], v1 = acc1[mi][ni];
            float* xo = Xout + (((size_t)(b * 512 + co0)) << 12) + sp;
            xo[0]        = fmaxf(fmaf(v1[0], LO_INV, v0[0]) + b4[0], 0.f);
            xo[4096]     = fmaxf(fmaf(v1[1], LO_INV, v0[1]) + b4[1], 0.f);
            xo[2 * 4096] = fmaxf(fmaf(v1[2], LO_INV, v0[2]) + b4[2], 0.f);
            xo[3 * 4096] = fmaxf(fmaf(v1[3], LO_INV, v0[3]) + b4[3], 0.f);
        }
    }
}

// =====================================================================
// Kernel 2: 1x1 heads v5 -- v2's proven structure (64 blocks x 256
// thr, W staged in Ws[54][256] LDS, broadcast ds_reads) + software-
// pipelined X loads (prefetch next ci-quad before current FMA chain).
// Loads-only reorder; per-thread FMA order UNCHANGED -> bit-identical.
// =====================================================================
__global__ __launch_bounds__(256) void heads_kernel(
    const float* __restrict__ X, const float* __restrict__ cls_w,
    const float* __restrict__ cls_b, const float* __restrict__ bbox_w,
    const float* __restrict__ bbox_b, const float* __restrict__ im_info,
    float* __restrict__ SC, float* __restrict__ BXo)
{
    __shared__ __attribute__((aligned(16))) float Ws[54][256];   // 55.3 KB
    const int tid = threadIdx.x;
    const int blk = blockIdx.x;            // 0..63
    const int b   = blk >> 4;
    const int s   = ((blk & 15) << 8) + tid;

    float acc[54];
#pragma unroll
    for (int j = 0; j < 18; j++) acc[j] = cls_b[j];
#pragma unroll
    for (int j = 0; j < 36; j++) acc[18 + j] = bbox_b[j];

    const float* xp = X + (size_t)b * CMID * 4096 + s;
    for (int c0 = 0; c0 < 512; c0 += 256) {
        __syncthreads();
        for (int e = tid; e < 54 * 256; e += 256) {
            int j = e >> 8, ci = e & 255;
            Ws[j][ci] = (j < 18) ? cls_w[j * 512 + c0 + ci]
                                 : bbox_w[(j - 18) * 512 + c0 + ci];
        }
        __syncthreads();
        // software pipeline: prefetch next quad of X before FMA chain
        float p0 = xp[(size_t)(c0 + 0) * 4096];
        float p1 = xp[(size_t)(c0 + 1) * 4096];
        float p2 = xp[(size_t)(c0 + 2) * 4096];
        float p3 = xp[(size_t)(c0 + 3) * 4096];
        for (int ci = 0; ci < 256; ci += 4) {
            const float x0 = p0, x1 = p1, x2 = p2, x3 = p3;
            if (ci + 4 < 256) {
                p0 = xp[(size_t)(c0 + ci + 4) * 4096];
                p1 = xp[(size_t)(c0 + ci + 5) * 4096];
                p2 = xp[(size_t)(c0 + ci + 6) * 4096];
                p3 = xp[(size_t)(c0 + ci + 7) * 4096];
            }
#pragma unroll
            for (int j = 0; j < 54; j++) {
                float4 w4 = *(const float4*)&Ws[j][ci];
                acc[j] = fmaf(x3, w4.w, fmaf(x2, w4.z, fmaf(x1, w4.y, fmaf(x0, w4.x, acc[j]))));
            }
        }
    }

    const float imh = im_info[b * 3 + 0];
    const float imw = im_info[b * 3 + 1];
    const int hh = s >> 6, ww = s & 63;
    const float cxa = 7.5f + 16.f * (float)ww;
    const float cya = 7.5f + 16.f * (float)hh;
    const float WA[9] = {184.f, 368.f, 736.f, 128.f, 256.f, 512.f, 88.f, 176.f, 352.f};
    const float HA[9] = {96.f, 192.f, 384.f, 128.f, 256.f, 512.f, 176.f, 352.f, 704.f};
    const size_t base = (size_t)b * NANCH + (size_t)s * 9;
#pragma unroll
    for (int c = 0; c < 9; c++) {
        float bg = acc[c], fg = acc[9 + c];
        float m  = fmaxf(bg, fg);
        float e0 = expf(bg - m), e1 = expf(fg - m);
        float p  = e1 / (e0 + e1);
        float dx = acc[18 + 4 * c], dy = acc[19 + 4 * c];
        float dw = acc[20 + 4 * c], dh = acc[21 + 4 * c];
        float wa = WA[c], ha = HA[c];
        float cx = dx * wa + cxa;
        float cy = dy * ha + cya;
        float pw = expf(dw) * wa;
        float ph = expf(dh) * ha;
        float x1 = cx - 0.5f * pw, y1 = cy - 0.5f * ph;
        float x2 = cx + 0.5f * pw, y2 = cy + 0.5f * ph;
        x1 = fminf(fmaxf(x1, 0.f), imw - 1.f);
        y1 = fminf(fmaxf(y1, 0.f), imh - 1.f);
        x2 = fminf(fmaxf(x2, 0.f), imw - 1.f);
        y2 = fminf(fmaxf(y2, 0.f), imh - 1.f);
        SC[base + c] = p;
        *(float4*)&BXo[(base + c) * 4] = make_float4(x1, y1, x2, y2);
    }
}

// =====================================================================
// Kernel 3: selsort (proven R10) -- radix-find ustar, compact >= ustar,
// bitonic sort desc (skewed), truncate at 6000 = exact ref top-6000.
// =====================================================================
__global__ __launch_bounds__(1024) void selsort_kernel(
    const float* __restrict__ SC, const float* __restrict__ BX,
    float* __restrict__ CSC, float* __restrict__ CBX, int* __restrict__ CIX)
{
    const int b = blockIdx.x, tid = threadIdx.x;
    const int lane = tid & 63, wv = tid >> 6;
    const float* sc = SC + (size_t)b * NANCH;
    const unsigned* bits = (const unsigned*)sc;

    __shared__ u64 sk[8704];                 // keys (skewed); u32 view = hist
    unsigned* s_buf = (unsigned*)sk;         // 8192 u32 = 32KB subset
    __shared__ unsigned s_part[1024];
    __shared__ unsigned s_wsum[16];
    __shared__ unsigned s_sel[2];
    __shared__ int s_cnt;
    auto P = [](int i) { return i + (i >> 4); };

    auto findbin = [&](int nb, int bpt, unsigned target) -> uint2 {
        unsigned mysum = 0;
        const int base = tid * bpt;
        if (base < nb)
            for (int q = 0; q < bpt; q++) mysum += s_buf[base + q];
        s_part[tid] = mysum;
        unsigned wsum = mysum;
#pragma unroll
        for (int off = 32; off; off >>= 1) wsum += __shfl_down(wsum, off);
        if (lane == 0) s_wsum[wv] = wsum;
        __syncthreads();
        unsigned cum = 0;
        for (int w = wv + 1; w < 16; w++) cum += s_wsum[w];
        for (int ll = lane + 1; ll < 64; ll++) cum += s_part[(wv << 6) + ll];
        if (base < nb) {
            unsigned c = cum;
            for (int q = bpt - 1; q >= 0; q--) {
                unsigned h = s_buf[base + q];
                if (c < target && c + h >= target) { s_sel[0] = base + q; s_sel[1] = c; }
                c += h;
            }
        }
        __syncthreads();
        uint2 r; r.x = s_sel[0]; r.y = s_sel[1];
        __syncthreads();
        return r;
    };

    // ---- 3-level radix to find ustar (6000th-largest raw bits) ----
    for (int i = tid; i < 8192; i += 1024) s_buf[i] = 0;
    __syncthreads();
    for (int i = tid; i < NANCH; i += 1024)
        atomicAdd(&s_buf[bits[i] >> 19], 1u);
    __syncthreads();
    uint2 r1 = findbin(8192, 8, PRE_N);
    const unsigned B1 = r1.x;
    unsigned target2 = PRE_N - r1.y;

    for (int i = tid; i < 8192; i += 1024) s_buf[i] = 0;
    __syncthreads();
    for (int i = tid; i < NANCH; i += 1024) {
        unsigned u = bits[i];
        if ((u >> 19) == B1) atomicAdd(&s_buf[(u >> 6) & 8191u], 1u);
    }
    __syncthreads();
    uint2 r2 = findbin(8192, 8, target2);
    const unsigned B2 = r2.x;
    unsigned target3 = target2 - r2.y;

    if (tid < 64) s_buf[tid] = 0;
    __syncthreads();
    const unsigned pref26 = (B1 << 13) | B2;
    for (int i = tid; i < NANCH; i += 1024) {
        unsigned u = bits[i];
        if ((u >> 6) == pref26) atomicAdd(&s_buf[u & 63u], 1u);
    }
    __syncthreads();
    uint2 r3 = findbin(64, 1, target3);
    const unsigned ustar = (B1 << 19) | (B2 << 6) | r3.x;

    // ---- compact all >= ustar into keys (count >= 6000 guaranteed) ----
    for (int i = tid; i < 8704; i += 1024) sk[i] = 0ull;   // filler sorts last
    if (tid == 0) s_cnt = 0;
    __syncthreads();
    for (int i = tid; i < NANCH; i += 1024) {
        unsigned u = bits[i];
        if (u >= ustar) {
            int p = atomicAdd(&s_cnt, 1);
            if (p < 8192)
                sk[P(p)] = ((u64)fflip(u) << 32) | (u64)(~((unsigned)i));
        }
    }
    __syncthreads();

    // ---- bitonic sort descending over 8192 (skewed index) ----
    for (int k = 2; k <= 8192; k <<= 1) {
        for (int j = k >> 1; j > 0; j >>= 1) {
            for (int t = tid; t < 8192; t += 1024) {
                int ixj = t ^ j;
                if (ixj > t) {
                    int pa = P(t), pb = P(ixj);
                    u64 a = sk[pa], c2 = sk[pb];
                    bool up = ((t & k) == 0);
                    if ((a < c2) == up) { sk[pa] = c2; sk[pb] = a; }
                }
            }
            __syncthreads();
        }
    }

    // ---- output: ranks < 6000 real (gather box), rest padded ----
    float* csc = CSC + (size_t)b * CAND_PAD;
    int*   cix = CIX + (size_t)b * CAND_PAD;
    float4* cbx4 = (float4*)CBX + (size_t)b * CAND_PAD;
    const float4* bx4 = (const float4*)BX + (size_t)b * NANCH;
    for (int i = tid; i < CAND_PAD; i += 1024) {
        if (i < PRE_N) {
            u64 key = sk[P(i)];
            unsigned khi = (unsigned)(key >> 32), klo = (unsigned)key;
            unsigned su = (khi & 0x80000000u) ? (khi ^ 0x80000000u) : ~khi;
            float scv = __uint_as_float(su);
            int ci = (int)(~klo);
            csc[i] = scv; cix[i] = ci;
            float4 pb;
            if (scv > -5.0e9f && (unsigned)ci < (unsigned)NANCH) pb = bx4[ci];
            else pb = make_float4(-4e9f, -4e9f, -4e9f, -4e9f);
            cbx4[i] = pb;
        } else {
            csc[i] = -2.0e10f;
            cix[i] = 0x7fffffff;
            cbx4[i] = make_float4(-4e9f, -4e9f, -4e9f, -4e9f);
        }
    }
}

// =====================================================================
// Kernel 4b: pairwise suppression bitmasks (proven).
// =====================================================================
__global__ __launch_bounds__(256) void nms_mask(
    const float* __restrict__ CBX, unsigned* __restrict__ MASK)
{
    const int rg = blockIdx.x, b = blockIdx.y, tid = threadIdx.x;
    const float4* cbx = (const float4*)CBX + (size_t)b * CAND_PAD;
    unsigned* mrow = MASK + (size_t)b * CAND_PAD * MWORDS;

    __shared__ float4 rb[64];
    __shared__ float  rar[64];
    __shared__ float4 cb[1024];
    __shared__ float  car[1024];

    if (tid < 64) {
        float4 v = cbx[rg * 64 + tid];
        rb[tid] = v;
        rar[tid] = (v.z - v.x + 1.f) * (v.w - v.y + 1.f);
    }
    __syncthreads();
    const int rl = tid >> 2;                  // row 0..63 within group
    const int wq = tid & 3;
    const float4 rv = rb[rl];
    const float  ra = rar[rl];
    const size_t rbase = (size_t)(rg * 64 + rl) * MWORDS;

    for (int jt = rg >> 4; jt < 6; jt++) {    // skip strictly-lower tiles
        __syncthreads();
        for (int e = tid; e < 1024; e += 256) {
            float4 v = cbx[jt * 1024 + e];
            cb[e] = v;
            car[e] = (v.z - v.x + 1.f) * (v.w - v.y + 1.f);
        }
        __syncthreads();
#pragma unroll
        for (int k = 0; k < 8; k++) {
            const int wt = wq + 4 * k;        // word in tile 0..31
            unsigned bits = 0;
            for (int bit = 0; bit < 32; bit++) {
                const int j = wt * 32 + bit;
                float4 cv = cb[j];
                float xx1 = fmaxf(rv.x, cv.x);
                float yy1 = fmaxf(rv.y, cv.y);
                float xx2 = fminf(rv.z, cv.z);
                float yy2 = fminf(rv.w, cv.w);
                float iw = fmaxf(xx2 - xx1 + 1.f, 0.f);
                float ih = fmaxf(yy2 - yy1 + 1.f, 0.f);
                float inter = iw * ih;
                float iou = inter / (ra + car[j] - inter);
                if (iou > 0.7f) bits |= (1u << bit);
            }
            mrow[rbase + jt * 32 + wt] = bits;
        }
    }
}

// =====================================================================
// Kernel 4c: scan v3 (proven) -- single wave, register removed-mask.
// =====================================================================
__global__ __launch_bounds__(64) void nms_scan(
    const float* __restrict__ CSC, const float* __restrict__ CBX,
    const unsigned* __restrict__ MASK, float* __restrict__ out)
{
    const int b = blockIdx.x, lane = threadIdx.x;
    const float*  csc = CSC + (size_t)b * CAND_PAD;
    const float4* cbx = (const float4*)CBX + (size_t)b * CAND_PAD;
    const unsigned* mk = MASK + (size_t)b * CAND_PAD * MWORDS;

    float* rois = out + (size_t)b * 1500;
    float* oscr = out + 6000 + (size_t)b * 300;

    for (int it = lane; it < POST_N; it += 64) {
        float* r = rois + it * 5;
        r[0] = (float)b; r[1] = 0.f; r[2] = 0.f; r[3] = 0.f; r[4] = 0.f;
        oscr[it] = 0.f;
    }
    __syncthreads();

    unsigned rm0 = 0u, rm1 = 0u, rm2 = 0u;   // removed words lane,+64,+128
    int cnt = 0;
    unsigned rlo = mk[(size_t)lane * MWORDS + 0];
    unsigned rhi = mk[(size_t)lane * MWORDS + 1];
    float    rsc = csc[lane];

    for (int c = 0; c < 94 && cnt < POST_N; c++) {
        const int W0 = 2 * c;
        const int slot = W0 >> 6;
        unsigned sel = (slot == 0) ? rm0 : (slot == 1) ? rm1 : rm2;
        unsigned gw = __shfl(sel, (W0 & 63) + (lane >> 5));
        bool alive = !((gw >> (lane & 31)) & 1u) && (rsc > -5.0e9f);
        u64 rem = __ballot(alive);
        u64 keptm = 0ull;
        while (rem) {
            int sl = __builtin_ctzll(rem);
            keptm |= 1ull << sl;
            unsigned blo = __shfl(rlo, sl);
            unsigned bhi = __shfl(rhi, sl);
            rem &= ~(((u64)bhi << 32) | (u64)blo);
            rem &= ~(1ull << sl);
        }
        if (c + 1 < 94) {
            const int i2 = (c + 1) * 64 + lane;
            rlo = mk[(size_t)i2 * MWORDS + 2 * (c + 1)];
            rhi = mk[(size_t)i2 * MWORDS + 2 * (c + 1) + 1];
            rsc = csc[i2];
        }
        while (keptm && cnt < POST_N) {
            int sl = __builtin_ctzll(keptm);
            keptm &= keptm - 1ull;
            const int i = c * 64 + sl;
            const size_t rb = (size_t)i * MWORDS;
            rm0 |= mk[rb + lane];
            rm1 |= mk[rb + lane + 64];
            rm2 |= mk[rb + lane + 128];
            if (lane == 0) {
                float4 pb = cbx[i];
                float* r = rois + cnt * 5;
                r[1] = pb.x; r[2] = pb.y; r[3] = pb.z; r[4] = pb.w;
                oscr[cnt] = csc[i];
            }
            cnt++;
        }
    }
}

// =====================================================================
extern "C" void kernel_launch(void* const* d_in, const int* in_sizes, int n_in,
                              void* d_out, int out_size, void* d_ws, size_t ws_size,
                              hipStream_t stream)
{
    const float* base_feat = (const float*)d_in[0];
    const float* im_info   = (const float*)d_in[1];
    const float* conv_w    = (const float*)d_in[4];
    const float* conv_b    = (const float*)d_in[5];
    const float* cls_w     = (const float*)d_in[6];
    const float* cls_b     = (const float*)d_in[7];
    const float* bbox_w    = (const float*)d_in[8];
    const float* bbox_b    = (const float*)d_in[9];

    float* ws  = (float*)d_ws;
    float* X   = ws + X_OFF;
    float* SC  = ws + SC_OFF;
    float* BX  = ws + BX_OFF;
    float* CSC = ws + CSC_OFF;
    float* CBX = ws + CBX_OFF;
    int*   CIX = (int*)(ws + CIX_OFF);
    u16*   WTH = (u16*)(ws + WTH_OFF);
    u16*   WTL = (u16*)(ws + WTL_OFF);
    u16*   XHp = (u16*)(ws + XH_OFF);
    u16*   XLp = (u16*)(ws + XL_OFF);
    float* ZPf = ws + ZP_OFF;
    const u16* ZPu = (const u16*)ZPf;
    unsigned* MASK = (unsigned*)(ws + X_OFF);   // aliases X (dead after heads)
    float* out = (float*)d_out;

    hipLaunchKernelGGL(prep_wtk, dim3(18432), dim3(256), 0, stream,
                       conv_w, WTH, WTL, ZPf);
    hipLaunchKernelGGL(prep_act, dim3(4096), dim3(256), 0, stream,
                       base_feat, XHp, XLp);
    hipLaunchKernelGGL(conv3_mfma, dim3(128, 4), dim3(256), 0, stream,
                       WTH, WTL, XHp, XLp, ZPu, conv_b, X);
    hipLaunchKernelGGL(heads_kernel, dim3(64), dim3(256), 0, stream,
                       X, cls_w, cls_b, bbox_w, bbox_b, im_info, SC, BX);
    hipLaunchKernelGGL(selsort_kernel, dim3(4), dim3(1024), 0, stream,
                       SC, BX, CSC, CBX, CIX);
    hipLaunchKernelGGL(nms_mask, dim3(96, 4), dim3(256), 0, stream,
                       CBX, MASK);
    hipLaunchKernelGGL(nms_scan, dim3(4), dim3(64), 0, stream,
                       CSC, CBX, MASK, out);
}